// Round 4
// baseline (18192.700 us; speedup 1.0000x reference)
//
#include <hip/hip_runtime.h>

#define B_SZ   256
#define D_IN   512
#define T_LEN  512
#define H_DIM  1024
#define KTOT   1536   // H_DIM + D_IN
#define NCLASS 1000

using half8   = __attribute__((ext_vector_type(8))) _Float16;
using floatx4 = __attribute__((ext_vector_type(4))) float;

__device__ __forceinline__ float ftanh(float x) {
    x = fminf(fmaxf(x, -20.f), 20.f);
    float e = __expf(2.f * x);
    return (e - 1.f) / (e + 1.f);
}

// ---------------------------------------------------------------------------
// Transpose x [B][D][T] fp32 -> xT [T][B][D] f16 (contraction-contiguous).
// ---------------------------------------------------------------------------
__global__ void k_transpose_x(const float* __restrict__ x, _Float16* __restrict__ xT) {
    __shared__ float tile[32][33];
    int b = blockIdx.z, d0 = blockIdx.y * 32, t0 = blockIdx.x * 32;
    int tx = threadIdx.x, ty = threadIdx.y;   // 32 x 8
    const float* xp = x + ((size_t)b * D_IN + d0) * T_LEN + t0;
#pragma unroll
    for (int i = 0; i < 4; ++i)
        tile[ty + i * 8][tx] = xp[(size_t)(ty + i * 8) * T_LEN + tx];
    __syncthreads();
#pragma unroll
    for (int i = 0; i < 4; ++i) {
        int t = t0 + ty + i * 8;
        xT[((size_t)t * B_SZ + b) * D_IN + d0 + tx] = (_Float16)tile[tx][ty + i * 8];
    }
}

// ---------------------------------------------------------------------------
// Build WcatT [4096][1536] f16, column-major weights: WcatT[n][k].
// n = gate*1024 + j, gate order g,f,i,o.  k<1024 -> Wh[k][j], k>=1024 -> Wx[k-1024][j].
// (R1-verified version.)
// ---------------------------------------------------------------------------
__global__ void k_build_wcat(const float* __restrict__ Wgh, const float* __restrict__ Wfh,
                             const float* __restrict__ Wih, const float* __restrict__ Woh,
                             const float* __restrict__ Wgx, const float* __restrict__ Wfx,
                             const float* __restrict__ Wix, const float* __restrict__ Wox,
                             _Float16* __restrict__ WcatT) {
    int src = blockIdx.z;                 // 0..3 = Wh g,f,i,o ; 4..7 = Wx g,f,i,o
    int kmax = (src < 4) ? 1024 : 512;
    int koff = (src < 4) ? 0 : 1024;
    int gi = src & 3;
    const float* W;
    switch (src) {
        case 0: W = Wgh; break; case 1: W = Wfh; break;
        case 2: W = Wih; break; case 3: W = Woh; break;
        case 4: W = Wgx; break; case 5: W = Wfx; break;
        case 6: W = Wix; break; default: W = Wox; break;
    }
    int k0 = blockIdx.y * 32;
    if (k0 >= kmax) return;
    int j0 = blockIdx.x * 32;
    __shared__ float tile[32][33];
    int tx = threadIdx.x, ty = threadIdx.y;   // 32 x 8
#pragma unroll
    for (int i = 0; i < 4; ++i)
        tile[ty + i * 8][tx] = W[(size_t)(k0 + ty + i * 8) * 1024 + j0 + tx];
    __syncthreads();
#pragma unroll
    for (int i = 0; i < 4; ++i) {
        int n = gi * 1024 + j0 + ty + i * 8;
        WcatT[(size_t)n * KTOT + koff + k0 + tx] = (_Float16)tile[tx][ty + i * 8];
    }
}

// ---------------------------------------------------------------------------
// Init: zero h buffer 0, concatenated bias (g,f,i,o), sync counters.
// (ws is re-poisoned before every timed call, so this must run every call.)
// ---------------------------------------------------------------------------
__global__ void k_init(unsigned int* __restrict__ h0u, float* __restrict__ bias,
                       unsigned int* __restrict__ cnt,
                       const float* __restrict__ bg, const float* __restrict__ bf,
                       const float* __restrict__ bi, const float* __restrict__ bo) {
    int idx = blockIdx.x * 256 + threadIdx.x;          // grid 512 -> 131072
    if (idx < 131072) h0u[idx] = 0u;                   // 262144 halves
    if (idx < 4096) {
        int gi = idx >> 10, j = idx & 1023;
        float v = (gi == 0) ? bg[j] : (gi == 1) ? bf[j] : (gi == 2) ? bi[j] : bo[j];
        bias[idx] = v;
    }
    if (idx < 256) cnt[idx] = 0u;
}

// ---------------------------------------------------------------------------
// Raw barrier: lgkmcnt(0) gives cross-wave LDS-write visibility; raw s_barrier
// does NOT drain vmcnt -> in-flight global prefetch survives.
// ---------------------------------------------------------------------------
__device__ __forceinline__ void bar() {
    asm volatile("s_waitcnt lgkmcnt(0)" ::: "memory");
    __builtin_amdgcn_s_barrier();
    asm volatile("" ::: "memory");
}

// ---------------------------------------------------------------------------
// PERSISTENT recurrence kernel: all 512 steps in one launch.
// Grid 256 blocks x 256 threads; 144 KB LDS forces 1 block/CU -> all blocks
// co-resident (256 blocks == 256 CUs).
// Block (rg, cg): 64 batch rows x 16 h-cols (all 4 gates). Wave w owns the
// 16-row band r0+16w : fully lane-local epilogue (R1-verified C/D layout).
// B(h-part) [4 gates][32 ksteps] lives in LDS for the whole kernel (128 KB).
// B(x-part) staged per step in 4 rounds of 16 KB. A fragments loaded DIRECT
// from plain row-major h / xT (a 16x16x32 A-frag = 16 rows x 64B = 16 cache
// lines = optimal coalescing; no swizzled copies needed).
// c-state lives in registers for all 512 steps.
// Inter-block sync: per-rg-group counter (64 producer blocks), release fence +
// atomicAdd after h write; consumers spin before their h-phase. The x-phase
// (no h dependency) runs BEFORE the spin to hide skew.
// ---------------------------------------------------------------------------
__global__ __launch_bounds__(256)
void k_persist(const _Float16* __restrict__ xT, const _Float16* __restrict__ WcatT,
               const float* __restrict__ bias, _Float16* __restrict__ hb0,
               _Float16* __restrict__ hb1, float* __restrict__ h_f32,
               unsigned int* __restrict__ cnt) {
    __shared__ __align__(16) _Float16 Bh[4 * 32 * 512];   // 128 cells x 512 halves = 128 KB
    __shared__ __align__(16) _Float16 Bxs[16 * 512];      // 16 cells = 16 KB

    int bid = blockIdx.x;
    int xcd = bid & 7, idx = bid >> 3;
    int cg = xcd * 8 + (idx & 7);     // [0,64) h-col group
    int rg = idx >> 3;                // [0,4)  batch group (64 rows)
    int r0 = rg * 64, hc0 = cg * 16;

    int tid = threadIdx.x, w = tid >> 6, l = tid & 63;
    int col = l & 15, q = l >> 4;     // fragment coords (verified m89 layout)
    int myrow = r0 + 16 * w;          // wave's row band

    int gcol = hc0 + col;
    float bg_ = bias[gcol],        bf_ = bias[1024 + gcol];
    float bi_ = bias[2048 + gcol], bo_ = bias[3072 + gcol];

    float c_[4] = {0.f, 0.f, 0.f, 0.f};   // c-state for rows myrow + q*4 + r

    // ---- prologue: load B(h) into LDS once (cells: cid = g*32 + hks) ----
#pragma unroll 4
    for (int i = 0; i < 32; ++i) {
        int cid = w + 4 * i;
        int g = cid >> 5, ks = cid & 31;
        half8 v = *(const half8*)(WcatT + (size_t)(g * 1024 + hc0 + col) * KTOT + ks * 32 + q * 8);
        *(half8*)&Bh[cid * 512 + l * 8] = v;
    }
    __syncthreads();

    unsigned int* myCnt = cnt + rg * 64;   // 256B-separated counters

#pragma unroll 1
    for (int t = 0; t < T_LEN; ++t) {
        const _Float16* hin  = (t & 1) ? hb1 : hb0;
        _Float16*       hout = (t & 1) ? hb0 : hb1;
        const _Float16* xt = xT + (size_t)t * (B_SZ * D_IN);

        floatx4 acc[4];
#pragma unroll
        for (int g = 0; g < 4; ++g) acc[g] = (floatx4){0.f, 0.f, 0.f, 0.f};

        // ---- X phase (independent of h): 4 rounds of 4 ksteps ----
        const _Float16* axbase = xt + (size_t)(myrow + col) * D_IN + q * 8;
#pragma unroll 1
        for (int r = 0; r < 4; ++r) {
            // wave w stages gate w's 4 ksteps of this round
#pragma unroll
            for (int e = 0; e < 4; ++e) {
                int xks = r * 4 + e;
                half8 v = *(const half8*)(WcatT + (size_t)(w * 1024 + hc0 + col) * KTOT
                                          + 1024 + xks * 32 + q * 8);
                *(half8*)&Bxs[(w * 4 + e) * 512 + l * 8] = v;
            }
            bar();
#pragma unroll
            for (int e = 0; e < 4; ++e) {
                int xks = r * 4 + e;
                half8 ax = *(const half8*)(axbase + xks * 32);
#pragma unroll
                for (int g = 0; g < 4; ++g)
                    acc[g] = __builtin_amdgcn_mfma_f32_16x16x32_f16(
                        ax, *(const half8*)&Bxs[(g * 4 + e) * 512 + l * 8], acc[g], 0, 0, 0);
            }
            bar();
        }

        // ---- wait for h[t-1] from this rg-group's 64 producers ----
        if (t > 0) {
            if (tid == 0) {
                unsigned int target = (unsigned int)(64 * t);
                while (__hip_atomic_load(myCnt, __ATOMIC_RELAXED, __HIP_MEMORY_SCOPE_AGENT) < target)
                    __builtin_amdgcn_s_sleep(2);
            }
            __syncthreads();
            __threadfence();   // acquire: invalidate L1/L2(sc1) before h reads
        }

        // ---- H phase: 32 ksteps, B from persistent LDS, A direct-global ----
        const _Float16* ahbase = hin + (size_t)(myrow + col) * H_DIM + q * 8;
        half8 ah[4];
#pragma unroll
        for (int p = 0; p < 4; ++p) ah[p] = *(const half8*)(ahbase + p * 32);
#pragma unroll
        for (int hks = 0; hks < 32; ++hks) {
            half8 a = ah[hks & 3];
            if (hks + 4 < 32) ah[hks & 3] = *(const half8*)(ahbase + (hks + 4) * 32);
#pragma unroll
            for (int g = 0; g < 4; ++g)
                acc[g] = __builtin_amdgcn_mfma_f32_16x16x32_f16(
                    a, *(const half8*)&Bh[(g * 32 + hks) * 512 + l * 8], acc[g], 0, 0, 0);
        }

        // ---- epilogue: gate math, c in regs, h write (layout verified m89) ----
#pragma unroll
        for (int r = 0; r < 4; ++r) {
            int grow = myrow + q * 4 + r;
            float g  = ftanh(acc[0][r] + bg_);
            float f  = ftanh(acc[1][r] + bf_);
            float ii = ftanh(acc[2][r] + bi_);
            float o  = ftanh(acc[3][r] + bo_);
            float cn = g * ii + c_[r] * f;
            c_[r] = cn;
            float hn = ftanh(cn) * o;
            hout[(size_t)grow * H_DIM + gcol] = (_Float16)hn;
            if (t == T_LEN - 1) h_f32[(size_t)grow * H_DIM + gcol] = hn;
        }

        // ---- signal: h[t] ready (syncthreads drains vmcnt on all waves) ----
        __syncthreads();
        if (tid == 0) {
            __threadfence();                 // release: write back dirty lines
            atomicAdd(myCnt, 1u);            // device-scope
        }
    }
}

// ---------------------------------------------------------------------------
// logits[256][1024(pad)] = h @ W_ph + b_p   (fp32 vector; tiny GEMM)
// ---------------------------------------------------------------------------
__global__ void k_logits(const float* __restrict__ h, const float* __restrict__ Wp,
                         const float* __restrict__ bp, float* __restrict__ logits) {
    __shared__ float hs[32][65];
    int r0 = blockIdx.y * 32;
    int c0 = blockIdx.x * 64;
    int tid = threadIdx.x;
    int wave = tid >> 6, tx = tid & 63;
    int col = c0 + tx;
    float s[8];
#pragma unroll
    for (int i = 0; i < 8; ++i) s[i] = 0.f;
    for (int kc = 0; kc < 16; ++kc) {
        int k0 = kc * 64;
#pragma unroll
        for (int i = 0; i < 8; ++i) {
            int idx = tid + i * 256;
            hs[idx >> 6][idx & 63] = h[(size_t)(r0 + (idx >> 6)) * H_DIM + k0 + (idx & 63)];
        }
        __syncthreads();
        if (col < NCLASS) {
            for (int kk = 0; kk < 64; ++kk) {
                float wv = Wp[(size_t)(k0 + kk) * NCLASS + col];
#pragma unroll
                for (int rr = 0; rr < 8; ++rr) s[rr] += hs[wave * 8 + rr][kk] * wv;
            }
        }
        __syncthreads();
    }
    if (col < NCLASS) {
#pragma unroll
        for (int rr = 0; rr < 8; ++rr)
            logits[(size_t)(r0 + wave * 8 + rr) * 1024 + col] = s[rr] + bp[col];
    }
}

// ---------------------------------------------------------------------------
// Row softmax over 1000 classes -> d_out [256][1000] fp32
// ---------------------------------------------------------------------------
__global__ void k_softmax(const float* __restrict__ logits, float* __restrict__ out) {
    __shared__ float red[256];
    int row = blockIdx.x, tid = threadIdx.x;
    float v[4];
    float mx = -1e30f;
#pragma unroll
    for (int i = 0; i < 4; ++i) {
        int c = tid + i * 256;
        float z = (c < NCLASS) ? logits[(size_t)row * 1024 + c] : -1e30f;
        v[i] = z;
        mx = fmaxf(mx, z);
    }
    red[tid] = mx; __syncthreads();
    for (int s = 128; s > 0; s >>= 1) {
        if (tid < s) red[tid] = fmaxf(red[tid], red[tid + s]);
        __syncthreads();
    }
    mx = red[0]; __syncthreads();
    float sum = 0.f;
#pragma unroll
    for (int i = 0; i < 4; ++i) {
        int c = tid + i * 256;
        v[i] = (c < NCLASS) ? __expf(v[i] - mx) : 0.f;
        sum += v[i];
    }
    red[tid] = sum; __syncthreads();
    for (int s = 128; s > 0; s >>= 1) {
        if (tid < s) red[tid] += red[tid + s];
        __syncthreads();
    }
    float inv = 1.f / red[0];
#pragma unroll
    for (int i = 0; i < 4; ++i) {
        int c = tid + i * 256;
        if (c < NCLASS) out[(size_t)row * NCLASS + c] = v[i] * inv;
    }
}

// ---------------------------------------------------------------------------
extern "C" void kernel_launch(void* const* d_in, const int* in_sizes, int n_in,
                              void* d_out, int out_size, void* d_ws, size_t ws_size,
                              hipStream_t stream) {
    const float* x   = (const float*)d_in[0];
    const float* Wfx = (const float*)d_in[1];
    const float* Wfh = (const float*)d_in[2];
    const float* Wgx = (const float*)d_in[3];
    const float* Wgh = (const float*)d_in[4];
    const float* Wix = (const float*)d_in[5];
    const float* Wih = (const float*)d_in[6];
    const float* Wox = (const float*)d_in[7];
    const float* Woh = (const float*)d_in[8];
    const float* Wph = (const float*)d_in[9];
    const float* bf  = (const float*)d_in[10];
    const float* bg  = (const float*)d_in[11];
    const float* bi  = (const float*)d_in[12];
    const float* bo  = (const float*)d_in[13];
    const float* bp  = (const float*)d_in[14];
    float* outp = (float*)d_out;

    char* ws = (char*)d_ws;
    _Float16*     xT    = (_Float16*)(ws);                       // 134217728
    _Float16*     WcatT = (_Float16*)(ws + 134217728);           // 12582912
    float*        bias  = (float*)   (ws + 146800640);           // 16384
    _Float16*     hb0   = (_Float16*)(ws + 146817024);           // 524288
    _Float16*     hb1   = (_Float16*)(ws + 147341312);           // 524288
    float*        hf32  = (float*)   (ws + 147865600);           // 1048576
    float*        logit = (float*)   (ws + 148914176);           // 1048576
    unsigned int* cnt   = (unsigned int*)(ws + 149962752);       // 1024

    k_transpose_x<<<dim3(16, 16, 256), dim3(32, 8), 0, stream>>>(x, xT);
    k_build_wcat<<<dim3(32, 32, 8), dim3(32, 8), 0, stream>>>(
        Wgh, Wfh, Wih, Woh, Wgx, Wfx, Wix, Wox, WcatT);
    k_init<<<512, 256, 0, stream>>>((unsigned int*)hb0, bias, cnt, bg, bf, bi, bo);

    k_persist<<<256, 256, 0, stream>>>(xT, WcatT, bias, hb0, hb1, hf32, cnt);

    k_logits<<<dim3(16, 8), 256, 0, stream>>>(hf32, Wph, bp, logit);
    k_softmax<<<256, 256, 0, stream>>>(logit, outp);
}

// Round 5
// 5593.990 us; speedup vs baseline: 3.2522x; 3.2522x over previous
//
#include <hip/hip_runtime.h>

#define B_SZ   256
#define D_IN   512
#define T_LEN  512
#define H_DIM  1024
#define KTOT   1536   // H_DIM + D_IN
#define NCLASS 1000

using half8    = __attribute__((ext_vector_type(8))) _Float16;
using floatx4  = __attribute__((ext_vector_type(4))) float;
using floatx16 = __attribute__((ext_vector_type(16))) float;

__device__ __forceinline__ float ftanh(float x) {
    x = fminf(fmaxf(x, -20.f), 20.f);
    float e = __expf(2.f * x);
    return (e - 1.f) / (e + 1.f);
}

// ---------------------------------------------------------------------------
// Transpose x [B][D][T] fp32 -> xT [T][B][D] f16 (contraction-contiguous).
// ---------------------------------------------------------------------------
__global__ void k_transpose_x(const float* __restrict__ x, _Float16* __restrict__ xT) {
    __shared__ float tile[32][33];
    int b = blockIdx.z, d0 = blockIdx.y * 32, t0 = blockIdx.x * 32;
    int tx = threadIdx.x, ty = threadIdx.y;   // 32 x 8
    const float* xp = x + ((size_t)b * D_IN + d0) * T_LEN + t0;
#pragma unroll
    for (int i = 0; i < 4; ++i)
        tile[ty + i * 8][tx] = xp[(size_t)(ty + i * 8) * T_LEN + tx];
    __syncthreads();
#pragma unroll
    for (int i = 0; i < 4; ++i) {
        int t = t0 + ty + i * 8;
        xT[((size_t)t * B_SZ + b) * D_IN + d0 + tx] = (_Float16)tile[tx][ty + i * 8];
    }
}

// ---------------------------------------------------------------------------
// Build WcatT [4096][1536] f16, column-major weights: WcatT[n][k].
// n = gate*1024 + j, gate order g,f,i,o.  k<1024 -> Wh[k][j], k>=1024 -> Wx[k-1024][j].
// ---------------------------------------------------------------------------
__global__ void k_build_wcat(const float* __restrict__ Wgh, const float* __restrict__ Wfh,
                             const float* __restrict__ Wih, const float* __restrict__ Woh,
                             const float* __restrict__ Wgx, const float* __restrict__ Wfx,
                             const float* __restrict__ Wix, const float* __restrict__ Wox,
                             _Float16* __restrict__ WcatT) {
    int src = blockIdx.z;                 // 0..3 = Wh g,f,i,o ; 4..7 = Wx g,f,i,o
    int kmax = (src < 4) ? 1024 : 512;
    int koff = (src < 4) ? 0 : 1024;
    int gi = src & 3;
    const float* W;
    switch (src) {
        case 0: W = Wgh; break; case 1: W = Wfh; break;
        case 2: W = Wih; break; case 3: W = Woh; break;
        case 4: W = Wgx; break; case 5: W = Wfx; break;
        case 6: W = Wix; break; default: W = Wox; break;
    }
    int k0 = blockIdx.y * 32;
    if (k0 >= kmax) return;
    int j0 = blockIdx.x * 32;
    __shared__ float tile[32][33];
    int tx = threadIdx.x, ty = threadIdx.y;   // 32 x 8
#pragma unroll
    for (int i = 0; i < 4; ++i)
        tile[ty + i * 8][tx] = W[(size_t)(k0 + ty + i * 8) * 1024 + j0 + tx];
    __syncthreads();
#pragma unroll
    for (int i = 0; i < 4; ++i) {
        int n = gi * 1024 + j0 + ty + i * 8;
        WcatT[(size_t)n * KTOT + koff + k0 + tx] = (_Float16)tile[tx][ty + i * 8];
    }
}

// ---------------------------------------------------------------------------
// Init: zero c, zero h buffer 0, build concatenated bias [4096] (g,f,i,o).
// ---------------------------------------------------------------------------
__global__ void k_init(float* __restrict__ c, unsigned int* __restrict__ h0u,
                       float* __restrict__ bias,
                       const float* __restrict__ bg, const float* __restrict__ bf,
                       const float* __restrict__ bi, const float* __restrict__ bo) {
    int idx = blockIdx.x * 256 + threadIdx.x;          // grid 1024 -> 262144
    if (idx < 262144) c[idx] = 0.f;
    if (idx < 131072) h0u[idx] = 0u;                   // 262144 halves
    if (idx < 4096) {
        int gi = idx >> 10, j = idx & 1023;
        float v = (gi == 0) ? bg[j] : (gi == 1) ? bf[j] : (gi == 2) ? bi[j] : bo[j];
        bias[idx] = v;
    }
}

// ---------------------------------------------------------------------------
// Raw barrier: lgkmcnt(0) gives cross-wave LDS-write visibility; raw s_barrier
// does NOT drain vmcnt -> in-flight global prefetch survives (R1-verified).
// ---------------------------------------------------------------------------
__device__ __forceinline__ void bar() {
    asm volatile("s_waitcnt lgkmcnt(0)" ::: "memory");
    __builtin_amdgcn_s_barrier();
    asm volatile("" ::: "memory");
}

// ---------------------------------------------------------------------------
// One recurrence step. Grid 256 x 512 threads (8 waves), 1 block/CU,
// 2 waves/SIMD (the latency-hiding R1 lacked).
// Block owns 64 batch rows (rg) x 16 h-cols (cg) = 64 n-cols (4 gates).
// Wave w: quadrant q=w&3 (qr=q&1 row-half, qc=q>>1 col-half, 32x32 output)
// x K-parity kh=w>>2 (kh=0 computes even chunks, kh=1 odd). SIMD s hosts
// waves s and s+4 (opposite parity) -> one computes while other stages.
// 24 K-chunks of 64; LDS double-buffer by chunk parity; reg prefetch depth 2;
// one raw barrier per chunk round (R1-verified skeleton).
// Epilogue: K-parity reduce + gate exchange via eps[2][64][65] (R2-verified
// 32x32 C/D layout: col=lane&31, row=4*(lane>>5)+(r&3)+8*(r>>2)).
// ---------------------------------------------------------------------------
__global__ __launch_bounds__(512)
void k_step(const _Float16* __restrict__ h_in, _Float16* __restrict__ h_out,
            float* __restrict__ h_f32, float* __restrict__ c_st,
            const _Float16* __restrict__ xTt, const _Float16* __restrict__ WcatT,
            const float* __restrict__ bias, int is_last) {
    __shared__ __align__(16) _Float16 As[2][64][72];   // 36 KB
    __shared__ __align__(16) _Float16 Bs[2][64][72];   // 36 KB
    __shared__ float eps[2][64][65];                   // 32.5 KB

    int bid = blockIdx.x;
    int xcd = bid & 7, idx = bid >> 3;
    int cg = xcd * 8 + (idx & 7);     // [0,64) h-col group -> same-XCD L2 locality
    int rg = idx >> 3;                // [0,4)  batch group (64 rows)
    int r0 = rg * 64, hc0 = cg * 16;

    int tid = threadIdx.x, w = tid >> 6, lane = tid & 63;
    int l31 = lane & 31, lh = lane >> 5;
    int q = w & 3, kh = w >> 2;
    int qr = q & 1, qc = q >> 1;

    floatx16 acc;
#pragma unroll
    for (int i = 0; i < 16; ++i) acc[i] = 0.f;

    // staging decomposition: 64 rows x 64 halves, 512 threads x 16 B each op
    int arow = tid >> 3, a8 = (tid & 7) << 3;
    const _Float16* hbase = h_in + (size_t)(r0 + arow) * H_DIM + a8;
    const _Float16* xbase = xTt + (size_t)(r0 + arow) * D_IN + a8;
    const _Float16* bbase = WcatT +
        (size_t)((arow >> 4) * 1024 + hc0 + (arow & 15)) * KTOT + a8;

    // c-state prefetch (items: row = (tid>>4)+32*ii, hcol = tid&15)
    int hcol = tid & 15;
    float cold[2];
    cold[0] = c_st[(size_t)(r0 + (tid >> 4)) * H_DIM + hc0 + hcol];
    cold[1] = c_st[(size_t)(r0 + 32 + (tid >> 4)) * H_DIM + hc0 + hcol];

#define LOADSET(A0, B0, c) do {                                                 \
        const _Float16* _sa = ((c) < 16) ? (hbase + ((c) << 6))                 \
                                         : (xbase + (((c) - 16) << 6));         \
        A0 = *(const uint4*)_sa;                                                \
        B0 = *(const uint4*)(bbase + ((c) << 6));                               \
    } while (0)

#define STORESET(A0, B0, buf) do {                                             \
        *(uint4*)&As[buf][arow][a8] = A0;                                      \
        *(uint4*)&Bs[buf][arow][a8] = B0;                                      \
    } while (0)

#define MFMA_CHUNK(buf) do {                                                    \
        _Pragma("unroll")                                                       \
        for (int ks = 0; ks < 4; ++ks) {                                        \
            half8 af  = *(const half8*)&As[buf][qr * 32 + l31][ks * 16 + lh * 8]; \
            half8 bf8 = *(const half8*)&Bs[buf][qc * 32 + l31][ks * 16 + lh * 8]; \
            acc = __builtin_amdgcn_mfma_f32_32x32x16_f16(af, bf8, acc, 0, 0, 0); \
        }                                                                       \
    } while (0)

    uint4 aE, bE;   // even-chunk prefetch stream
    uint4 aO, bO;   // odd-chunk prefetch stream

    // prologue: buf0 <- chunk0; regs: O = chunk1, E = chunk2 (in flight)
    LOADSET(aE, bE, 0);
    LOADSET(aO, bO, 1);
    STORESET(aE, bE, 0);
    LOADSET(aE, bE, 2);
    bar();

#pragma unroll
    for (int cc = 0; cc < 12; ++cc) {
        const int e = 2 * cc, o = e + 1;
        // invariant: buf0 = chunk e ready; regs O = chunk o; E = chunk e+2 in flight
        STORESET(aO, bO, 1);                       // stage chunk o -> buf1
        if (kh == 0) MFMA_CHUNK(0);                // even-parity waves compute e
        if (o + 2 < 24) LOADSET(aO, bO, o + 2);
        bar();
        if (e + 2 < 24) STORESET(aE, bE, 0);       // stage chunk e+2 -> buf0
        if (kh == 1) MFMA_CHUNK(1);                // odd-parity waves compute o
        if (e + 4 < 24) LOADSET(aE, bE, e + 4);
        bar();
    }

#undef LOADSET
#undef STORESET
#undef MFMA_CHUNK

    // ---- epilogue: K-parity reduce + gate math ---------------------------
    // C/D layout (R2-verified): col = lane&31, row = 4*(lane>>5)+(r&3)+8*(r>>2)
#pragma unroll
    for (int r = 0; r < 16; ++r) {
        int rowm = qr * 32 + 4 * lh + (r & 3) + 8 * (r >> 2);
        eps[kh][rowm][qc * 32 + l31] = acc[r];
    }
    __syncthreads();

    float bg_ = bias[hc0 + hcol],        bf_ = bias[1024 + hc0 + hcol];
    float bi_ = bias[2048 + hc0 + hcol], bo_ = bias[3072 + hc0 + hcol];
#pragma unroll
    for (int ii = 0; ii < 2; ++ii) {
        int row = (tid >> 4) + 32 * ii;
        size_t off = (size_t)(r0 + row) * H_DIM + hc0 + hcol;
        float pg = eps[0][row][hcol]      + eps[1][row][hcol];
        float pf = eps[0][row][16 + hcol] + eps[1][row][16 + hcol];
        float pi = eps[0][row][32 + hcol] + eps[1][row][32 + hcol];
        float po = eps[0][row][48 + hcol] + eps[1][row][48 + hcol];
        float g  = ftanh(pg + bg_);
        float f  = ftanh(pf + bf_);
        float iy = ftanh(pi + bi_);
        float o  = ftanh(po + bo_);
        float cn = g * iy + cold[ii] * f;
        c_st[off] = cn;
        float hn = ftanh(cn) * o;
        h_out[off] = (_Float16)hn;
        if (is_last) h_f32[off] = hn;
    }
}

// ---------------------------------------------------------------------------
// logits[256][1024(pad)] = h @ W_ph + b_p   (fp32 vector; tiny GEMM)
// ---------------------------------------------------------------------------
__global__ void k_logits(const float* __restrict__ h, const float* __restrict__ Wp,
                         const float* __restrict__ bp, float* __restrict__ logits) {
    __shared__ float hs[32][65];
    int r0 = blockIdx.y * 32;
    int c0 = blockIdx.x * 64;
    int tid = threadIdx.x;
    int wave = tid >> 6, tx = tid & 63;
    int col = c0 + tx;
    float s[8];
#pragma unroll
    for (int i = 0; i < 8; ++i) s[i] = 0.f;
    for (int kc = 0; kc < 16; ++kc) {
        int k0 = kc * 64;
#pragma unroll
        for (int i = 0; i < 8; ++i) {
            int idx = tid + i * 256;
            hs[idx >> 6][idx & 63] = h[(size_t)(r0 + (idx >> 6)) * H_DIM + k0 + (idx & 63)];
        }
        __syncthreads();
        if (col < NCLASS) {
            for (int kk = 0; kk < 64; ++kk) {
                float wv = Wp[(size_t)(k0 + kk) * NCLASS + col];
#pragma unroll
                for (int rr = 0; rr < 8; ++rr) s[rr] += hs[wave * 8 + rr][kk] * wv;
            }
        }
        __syncthreads();
    }
    if (col < NCLASS) {
#pragma unroll
        for (int rr = 0; rr < 8; ++rr)
            logits[(size_t)(r0 + wave * 8 + rr) * 1024 + col] = s[rr] + bp[col];
    }
}

// ---------------------------------------------------------------------------
// Row softmax over 1000 classes -> d_out [256][1000] fp32
// ---------------------------------------------------------------------------
__global__ void k_softmax(const float* __restrict__ logits, float* __restrict__ out) {
    __shared__ float red[256];
    int row = blockIdx.x, tid = threadIdx.x;
    float v[4];
    float mx = -1e30f;
#pragma unroll
    for (int i = 0; i < 4; ++i) {
        int c = tid + i * 256;
        float z = (c < NCLASS) ? logits[(size_t)row * 1024 + c] : -1e30f;
        v[i] = z;
        mx = fmaxf(mx, z);
    }
    red[tid] = mx; __syncthreads();
    for (int s = 128; s > 0; s >>= 1) {
        if (tid < s) red[tid] = fmaxf(red[tid], red[tid + s]);
        __syncthreads();
    }
    mx = red[0]; __syncthreads();
    float sum = 0.f;
#pragma unroll
    for (int i = 0; i < 4; ++i) {
        int c = tid + i * 256;
        v[i] = (c < NCLASS) ? __expf(v[i] - mx) : 0.f;
        sum += v[i];
    }
    red[tid] = sum; __syncthreads();
    for (int s = 128; s > 0; s >>= 1) {
        if (tid < s) red[tid] += red[tid + s];
        __syncthreads();
    }
    float inv = 1.f / red[0];
#pragma unroll
    for (int i = 0; i < 4; ++i) {
        int c = tid + i * 256;
        if (c < NCLASS) out[(size_t)row * NCLASS + c] = v[i] * inv;
    }
}

// ---------------------------------------------------------------------------
extern "C" void kernel_launch(void* const* d_in, const int* in_sizes, int n_in,
                              void* d_out, int out_size, void* d_ws, size_t ws_size,
                              hipStream_t stream) {
    const float* x   = (const float*)d_in[0];
    const float* Wfx = (const float*)d_in[1];
    const float* Wfh = (const float*)d_in[2];
    const float* Wgx = (const float*)d_in[3];
    const float* Wgh = (const float*)d_in[4];
    const float* Wix = (const float*)d_in[5];
    const float* Wih = (const float*)d_in[6];
    const float* Wox = (const float*)d_in[7];
    const float* Woh = (const float*)d_in[8];
    const float* Wph = (const float*)d_in[9];
    const float* bf  = (const float*)d_in[10];
    const float* bg  = (const float*)d_in[11];
    const float* bi  = (const float*)d_in[12];
    const float* bo  = (const float*)d_in[13];
    const float* bp  = (const float*)d_in[14];
    float* outp = (float*)d_out;

    char* ws = (char*)d_ws;
    _Float16* xT    = (_Float16*)(ws);                       // 134217728
    _Float16* WcatT = (_Float16*)(ws + 134217728);           // 12582912
    float*    bias  = (float*)   (ws + 146800640);           // 16384
    _Float16* hb0   = (_Float16*)(ws + 146817024);           // 524288
    _Float16* hb1   = (_Float16*)(ws + 147341312);           // 524288
    float*    c_st  = (float*)   (ws + 147865600);           // 1048576
    float*    hf32  = (float*)   (ws + 148914176);           // 1048576
    float*    logit = (float*)   (ws + 149962752);           // 1048576

    k_transpose_x<<<dim3(16, 16, 256), dim3(32, 8), 0, stream>>>(x, xT);
    k_build_wcat<<<dim3(32, 32, 8), dim3(32, 8), 0, stream>>>(
        Wgh, Wfh, Wih, Woh, Wgx, Wfx, Wix, Wox, WcatT);
    k_init<<<1024, 256, 0, stream>>>(c_st, (unsigned int*)hb0, bias, bg, bf, bi, bo);

    for (int t = 0; t < T_LEN; ++t) {
        const _Float16* hin = (t & 1) ? hb1 : hb0;
        _Float16*       hout = (t & 1) ? hb0 : hb1;
        k_step<<<256, 512, 0, stream>>>(hin, hout, hf32, c_st,
                                        xT + (size_t)t * B_SZ * D_IN, WcatT, bias,
                                        (t == T_LEN - 1) ? 1 : 0);
    }

    k_logits<<<dim3(16, 8), 256, 0, stream>>>(hf32, Wph, bp, logit);
    k_softmax<<<256, 256, 0, stream>>>(logit, outp);
}